// Round 5
// baseline (385.826 us; speedup 1.0000x reference)
//
#include <hip/hip_runtime.h>

#define EPS 1e-6f
#define MAX_C 1000     // problem-fixed class count
#define W 32           // columns per slice-block (acc = 1000*32*4 = 125 KB LDS)
#define RPC 4096       // rows per chunk (131072 / 32)
#define SBLK 1024      // 16 waves

// ws layout (4-byte elems):
//   [0]      int   counts[C]
//   [C]      float loss_acc
//   [C+1]    float npres_acc
//   [C+2]    int   done
//   [C+3]    float partials[NCHUNKS * C * D]   (32 MB; fully overwritten)
// memset zeroes the first C+3 elems only.

// Direct-stream LDS-atomic scatter segment-sum.
// Block (slice, chunk): each wave keeps 8 independent 1 KB row-slice gathers
// in flight (coalesced: 8 rows x 128 B cache lines per load instr), then
// scatters via ds_add_f32 (no return value -> no dependent chain, no ballot,
// no cross-lane bookkeeping). Rotation swizzle (col + label) & 31 spreads
// same-column traffic across banks (~2-way, free). Zero global atomics in
// the hot loop; per-class counts come from the slice-0 prologue histogram.
__global__ __launch_bounds__(SBLK, 4)
void stream_kernel(const float* __restrict__ feats,
                   const int* __restrict__ lbls,
                   float* __restrict__ partials,
                   int* __restrict__ counts,
                   int n, int d, int nslices, int c_total) {
    int slice = blockIdx.x % nslices;
    int chunk = blockIdx.x / nslices;
    int t    = threadIdx.x;
    int wave = t >> 6;
    int lane = t & 63;
    int rg   = lane >> 3;     // row within 8-row load group
    int cg   = lane & 7;      // float4 column group within the 32-col slice

    __shared__ float acc[MAX_C * W];   // 125 KB
    __shared__ int   hist[MAX_C];      // 4 KB (slice-0 prologue only)

    int cW = c_total * W;
    int base = chunk * RPC;
    int rows = RPC; if (base + rows > n) rows = n - base;

    const float* fbase = feats + (size_t)base * d + slice * W;
    const int*   lbase = lbls + base;

    for (int i = t; i < cW; i += SBLK) acc[i] = 0.0f;

    // slice-0 blocks produce the per-class counts (LDS-privatized, out of loop)
    if (slice == 0) {
        for (int i = t; i < c_total; i += SBLK) hist[i] = 0;
        __syncthreads();
        for (int i = t; i < rows; i += SBLK) atomicAdd(&hist[lbase[i]], 1);
        __syncthreads();
        for (int i = t; i < c_total; i += SBLK) {
            int h = hist[i];
            if (h) atomicAdd(&counts[i], h);
        }
    }
    __syncthreads();          // acc zeroed (and counts flushed)

    // each wave sweeps 64 rows per iteration: lane covers rows rb+rg+8k, k=0..7
    const float4 z4 = make_float4(0.f, 0.f, 0.f, 0.f);
    for (int rb = wave * 64; rb < rows; rb += 64 * (SBLK / 64)) {
        int r0 = rb + rg;
        bool o0 = r0        < rows, o1 = r0 + 8  < rows;
        bool o2 = r0 + 16   < rows, o3 = r0 + 24 < rows;
        bool o4 = r0 + 32   < rows, o5 = r0 + 40 < rows;
        bool o6 = r0 + 48   < rows, o7 = r0 + 56 < rows;
        // 8 independent 1 KB gathers + 8 broadcast label loads in flight
        float4 v0 = o0 ? *(const float4*)(fbase + (size_t)(r0     ) * d + cg * 4) : z4;
        float4 v1 = o1 ? *(const float4*)(fbase + (size_t)(r0 +  8) * d + cg * 4) : z4;
        float4 v2 = o2 ? *(const float4*)(fbase + (size_t)(r0 + 16) * d + cg * 4) : z4;
        float4 v3 = o3 ? *(const float4*)(fbase + (size_t)(r0 + 24) * d + cg * 4) : z4;
        float4 v4 = o4 ? *(const float4*)(fbase + (size_t)(r0 + 32) * d + cg * 4) : z4;
        float4 v5 = o5 ? *(const float4*)(fbase + (size_t)(r0 + 40) * d + cg * 4) : z4;
        float4 v6 = o6 ? *(const float4*)(fbase + (size_t)(r0 + 48) * d + cg * 4) : z4;
        float4 v7 = o7 ? *(const float4*)(fbase + (size_t)(r0 + 56) * d + cg * 4) : z4;
        int l0 = o0 ? lbase[r0     ] : 0;
        int l1 = o1 ? lbase[r0 +  8] : 0;
        int l2 = o2 ? lbase[r0 + 16] : 0;
        int l3 = o3 ? lbase[r0 + 24] : 0;
        int l4 = o4 ? lbase[r0 + 32] : 0;
        int l5 = o5 ? lbase[r0 + 40] : 0;
        int l6 = o6 ? lbase[r0 + 48] : 0;
        int l7 = o7 ? lbase[r0 + 56] : 0;

#define SCAT(o, l, v)                                            \
        if (o) {                                                 \
            int b_ = (l) * W, c_ = cg * 4 + (l);                 \
            atomicAdd(&acc[b_ + ((c_ + 0) & (W - 1))], (v).x);   \
            atomicAdd(&acc[b_ + ((c_ + 1) & (W - 1))], (v).y);   \
            atomicAdd(&acc[b_ + ((c_ + 2) & (W - 1))], (v).z);   \
            atomicAdd(&acc[b_ + ((c_ + 3) & (W - 1))], (v).w);   \
        }
        SCAT(o0, l0, v0) SCAT(o1, l1, v1) SCAT(o2, l2, v2) SCAT(o3, l3, v3)
        SCAT(o4, l4, v4) SCAT(o5, l5, v5) SCAT(o6, l6, v6) SCAT(o7, l7, v7)
#undef SCAT
    }
    __syncthreads();          // all scatters complete

    // flush (unswizzle): partials[chunk][cls*d + slice*W + lc], coalesced 128 B
    float* pbase = partials + (size_t)chunk * c_total * d + slice * W;
    for (int i = t; i < cW; i += SBLK) {
        int cls  = i >> 5;               // / W
        int phys = i & (W - 1);
        int lc   = (phys - cls) & (W - 1);
        pbase[(size_t)cls * d + lc] = acc[i];
    }
}

// one block per class: sum chunk partials, Mahalanobis, global scalar reduce;
// last block to finish computes the final scalar (device-scope atomic read).
__global__ __launch_bounds__(256)
void finalize_kernel(const float* __restrict__ partials,
                     const int* __restrict__ counts,
                     const float* __restrict__ proto,
                     const float* __restrict__ cov,
                     float* __restrict__ loss_acc,
                     float* __restrict__ npres_acc,
                     int* __restrict__ done,
                     float* __restrict__ out, int c_total, int d, int nchunks) {
    int c = blockIdx.x;
    int t = threadIdx.x;
    size_t idx = (size_t)c * d + t;
    size_t cstride = (size_t)c_total * d;

    float a = 0.0f;
    for (int k = 0; k < nchunks; ++k)
        a += partials[(size_t)k * cstride + idx];

    int cnt = counts[c];
    float present = (cnt > 0) ? 1.0f : 0.0f;
    float mean = a / fmaxf((float)cnt, 1.0f);
    float diff = mean - proto[idx];
    float pe = present * diff * diff / (cov[idx] + EPS);

    for (int off = 32; off > 0; off >>= 1)
        pe += __shfl_down(pe, off, 64);
    __shared__ float s[4];
    if ((t & 63) == 0) s[t >> 6] = pe;
    __syncthreads();
    if (t == 0) {
        atomicAdd(loss_acc, (s[0] + s[1]) + (s[2] + s[3]));
        atomicAdd(npres_acc, present);
        __threadfence();
        int prev = atomicAdd(done, 1);
        if (prev == c_total - 1) {
            float L = atomicAdd(loss_acc, 0.0f);   // coherent read
            float P = atomicAdd(npres_acc, 0.0f);
            out[0] = L / (P * (float)d);
        }
    }
}

extern "C" void kernel_launch(void* const* d_in, const int* in_sizes, int n_in,
                              void* d_out, int out_size, void* d_ws, size_t ws_size,
                              hipStream_t stream) {
    const float* feats = (const float*)d_in[0];
    const int*   lbls  = (const int*)d_in[1];
    const float* proto = (const float*)d_in[2];
    const float* cov   = (const float*)d_in[3];

    int n_rows = in_sizes[1];              // N = 131072
    int d      = in_sizes[0] / n_rows;     // D = 256
    int c      = in_sizes[2] / d;          // C = 1000

    int*   counts    = (int*)d_ws;
    float* loss_acc  = (float*)d_ws + c;
    float* npres_acc = loss_acc + 1;
    int*   done      = (int*)d_ws + c + 2;
    float* partials  = (float*)d_ws + c + 3;

    hipMemsetAsync(d_ws, 0, ((size_t)c + 3) * sizeof(int), stream);

    int nslices = d / W;                               // 8
    int nchunks = (n_rows + RPC - 1) / RPC;            // 32
    stream_kernel<<<nslices * nchunks, SBLK, 0, stream>>>(
        feats, lbls, partials, counts, n_rows, d, nslices, c);
    finalize_kernel<<<c, 256, 0, stream>>>(partials, counts, proto, cov,
                                           loss_acc, npres_acc, done,
                                           (float*)d_out, c, d, nchunks);
}

// Round 6
// 270.545 us; speedup vs baseline: 1.4261x; 1.4261x over previous
//
#include <hip/hip_runtime.h>

#define EPS 1e-6f
#define MAX_C 1000     // problem-fixed class count
#define W 32           // columns per slice-block (acc = 1000*32*4 = 125 KB LDS)
#define TR 128         // rows per tile (stage buf = 16 KB, double-buffered)
#define RPC 4096       // rows per chunk (131072 / 32)
#define SBLK 1024      // 16 waves

// ws layout (4-byte elems):
//   [0]      int   counts[C]
//   [C]      float loss_acc
//   [C+1]    float npres_acc
//   [C+2]    int   done
//   [C+3]    float partials[NCHUNKS * C * D]   (32 MB; fully overwritten)
// memset zeroes the first C+3 elems only.

// global->LDS DMA: no VGPR round-trip, MLP decoupled from register budget.
// dst is wave-uniform base; lane writes at base + lane*size. src is per-lane.
__device__ __forceinline__ void dma16(const float* g, float* l) {
    __builtin_amdgcn_global_load_lds(
        (const __attribute__((address_space(1))) unsigned int*)g,
        (__attribute__((address_space(3))) unsigned int*)l, 16, 0, 0);
}
__device__ __forceinline__ void dma4(const int* g, int* l) {
    __builtin_amdgcn_global_load_lds(
        (const __attribute__((address_space(1))) unsigned int*)g,
        (__attribute__((address_space(3))) unsigned int*)l, 4, 0, 0);
}

// Streaming scatter segment-sum: DMA-staged tiles + wave-owned LDS RMW.
// Block (slice, chunk) pipelines 128-row tiles of its 32-col slice through a
// double-buffered LDS stage via global_load_lds (1 KB DMA per wave per tile).
// Wave w exclusively owns classes with (label & 15) == w, so accumulation is
// plain conflict-free LDS read-add-write (half-wave = row, lane = column).
// One raw s_barrier + own-wave vmcnt(0) per tile; DMA of tile t+1 overlaps
// processing of tile t.
__global__ __launch_bounds__(SBLK)
void stream_kernel(const float* __restrict__ feats,
                   const int* __restrict__ lbls,
                   float* __restrict__ partials,
                   int* __restrict__ counts,
                   int n, int d, int nslices, int c_total) {
    int slice = blockIdx.x % nslices;
    int chunk = blockIdx.x / nslices;
    int t    = threadIdx.x;
    int wv   = t >> 6;          // wave 0..15 = class-group owner
    int lane = t & 63;
    int half = lane >> 5;
    int col  = lane & 31;

    __shared__ float acc[MAX_C * W];        // 125 KB
    __shared__ float stage[2][TR * W];      // 2 x 16 KB (histo scratch first)
    __shared__ int   lbl_s[2][TR];          // 2 x 512 B

    int cW = c_total * W;
    int base = chunk * RPC;
    int rows = RPC; if (base + rows > n) rows = n - base;
    if (rows < 0) rows = 0;
    int ntiles = (rows + TR - 1) / TR;

    const float* fbase = feats + (size_t)base * d + slice * W;
    const int*   lbase = lbls + base;

    for (int i = t; i < cW; i += SBLK) acc[i] = 0.0f;

    // slice-0 blocks produce per-class counts (stage buffer reused as scratch)
    if (slice == 0) {
        int* hist = (int*)&stage[0][0];
        for (int i = t; i < c_total; i += SBLK) hist[i] = 0;
        __syncthreads();
        for (int i = t; i < rows; i += SBLK) atomicAdd(&hist[lbase[i]], 1);
        __syncthreads();
        for (int i = t; i < c_total; i += SBLK) {
            int h = hist[i];
            if (h) atomicAdd(&counts[i], h);
        }
    }
    __syncthreads();            // acc zeroed, hist scratch done

    // per-tile DMA: wave wv stages rows [8*wv, 8*wv+8) of the tile (1 KB);
    // wave 0 additionally stages the tile's 128 labels (2 x 4B-DMA).
    int drow = wv * 8 + (lane >> 3);        // row within tile this lane feeds
    int dcol = (lane & 7) * 4;              // float column within slice
    auto issue_dma = [&](int tile, int buf) {
        int r = tile * TR + drow; if (r > rows - 1) r = rows - 1;   // clamp (tail)
        dma16(fbase + (size_t)r * d + dcol, &stage[buf][wv * 256]);
        if (wv == 0) {
            int r0 = tile * TR + lane;       if (r0 > rows - 1) r0 = rows - 1;
            int r1 = tile * TR + 64 + lane;  if (r1 > rows - 1) r1 = rows - 1;
            dma4(lbase + r0, &lbl_s[buf][0]);
            dma4(lbase + r1, &lbl_s[buf][64]);
        }
    };

    if (ntiles > 0) issue_dma(0, 0);

    for (int tile = 0; tile < ntiles; ++tile) {
        int cur = tile & 1;
        asm volatile("s_waitcnt vmcnt(0)" ::: "memory");
        __builtin_amdgcn_s_barrier();       // tile data in LDS; prev buf free
        if (tile + 1 < ntiles) issue_dma(tile + 1, cur ^ 1);   // overlaps compute

        const float* stg = &stage[cur][0];
        int tb = tile * TR;
        int l0 = lbl_s[cur][lane];
        int l1 = lbl_s[cur][64 + lane];
        unsigned long long m0 = __ballot((tb + lane      < rows) && ((l0 & 15) == wv));
        unsigned long long m1 = __ballot((tb + 64 + lane < rows) && ((l1 & 15) == wv));

        // retire 2 rows per iteration: half-wave = row, lane&31 = column;
        // conflict-free by ownership (different waves -> different classes)
#define RUN(mask, lv, rbase)                                              \
        while (mask) {                                                    \
            int bA = (int)__ffsll(mask) - 1; mask &= mask - 1;            \
            int bB = -1;                                                  \
            if (mask) { bB = (int)__ffsll(mask) - 1; mask &= mask - 1; }  \
            int lA = __shfl(lv, bA);                                      \
            int lB = (bB >= 0) ? __shfl(lv, bB) : -1;                     \
            if (bB >= 0 && lB == lA) {                                    \
                if (half == 0) {                                          \
                    float v = stg[(rbase + bA) * W + col]                 \
                            + stg[(rbase + bB) * W + col];                \
                    acc[lA * W + col] += v;                               \
                }                                                         \
            } else {                                                      \
                int b_ = half ? bB : bA;                                  \
                int l_ = half ? lB : lA;                                  \
                if (b_ >= 0)                                              \
                    acc[l_ * W + col] += stg[(rbase + b_) * W + col];     \
            }                                                             \
        }
        RUN(m0, l0, 0)
        RUN(m1, l1, 64)
#undef RUN
    }
    __syncthreads();            // all acc writes visible for flush

    // flush: partials[chunk][cls*d + slice*W + col] — coalesced 128 B per class
    float* pbase = partials + (size_t)chunk * c_total * d + slice * W;
    for (int i = t; i < cW; i += SBLK) {
        int cls = i >> 5;
        int cc  = i & (W - 1);
        pbase[(size_t)cls * d + cc] = acc[i];
    }
}

// one block per class: sum chunk partials, Mahalanobis, global scalar reduce;
// last block to finish computes the final scalar (device-scope atomic read).
__global__ __launch_bounds__(256)
void finalize_kernel(const float* __restrict__ partials,
                     const int* __restrict__ counts,
                     const float* __restrict__ proto,
                     const float* __restrict__ cov,
                     float* __restrict__ loss_acc,
                     float* __restrict__ npres_acc,
                     int* __restrict__ done,
                     float* __restrict__ out, int c_total, int d, int nchunks) {
    int c = blockIdx.x;
    int t = threadIdx.x;
    size_t idx = (size_t)c * d + t;
    size_t cstride = (size_t)c_total * d;

    float a = 0.0f;
    for (int k = 0; k < nchunks; ++k)
        a += partials[(size_t)k * cstride + idx];

    int cnt = counts[c];
    float present = (cnt > 0) ? 1.0f : 0.0f;
    float mean = a / fmaxf((float)cnt, 1.0f);
    float diff = mean - proto[idx];
    float pe = present * diff * diff / (cov[idx] + EPS);

    for (int off = 32; off > 0; off >>= 1)
        pe += __shfl_down(pe, off, 64);
    __shared__ float s[4];
    if ((t & 63) == 0) s[t >> 6] = pe;
    __syncthreads();
    if (t == 0) {
        atomicAdd(loss_acc, (s[0] + s[1]) + (s[2] + s[3]));
        atomicAdd(npres_acc, present);
        __threadfence();
        int prev = atomicAdd(done, 1);
        if (prev == c_total - 1) {
            float L = atomicAdd(loss_acc, 0.0f);   // coherent read
            float P = atomicAdd(npres_acc, 0.0f);
            out[0] = L / (P * (float)d);
        }
    }
}

extern "C" void kernel_launch(void* const* d_in, const int* in_sizes, int n_in,
                              void* d_out, int out_size, void* d_ws, size_t ws_size,
                              hipStream_t stream) {
    const float* feats = (const float*)d_in[0];
    const int*   lbls  = (const int*)d_in[1];
    const float* proto = (const float*)d_in[2];
    const float* cov   = (const float*)d_in[3];

    int n_rows = in_sizes[1];              // N = 131072
    int d      = in_sizes[0] / n_rows;     // D = 256
    int c      = in_sizes[2] / d;          // C = 1000

    int*   counts    = (int*)d_ws;
    float* loss_acc  = (float*)d_ws + c;
    float* npres_acc = loss_acc + 1;
    int*   done      = (int*)d_ws + c + 2;
    float* partials  = (float*)d_ws + c + 3;

    hipMemsetAsync(d_ws, 0, ((size_t)c + 3) * sizeof(int), stream);

    int nslices = d / W;                               // 8
    int nchunks = (n_rows + RPC - 1) / RPC;            // 32
    stream_kernel<<<nslices * nchunks, SBLK, 0, stream>>>(
        feats, lbls, partials, counts, n_rows, d, nslices, c);
    finalize_kernel<<<c, 256, 0, stream>>>(partials, counts, proto, cov,
                                           loss_acc, npres_acc, done,
                                           (float*)d_out, c, d, nchunks);
}